// Round 1
// baseline (991.472 us; speedup 1.0000x reference)
//
#include <hip/hip_runtime.h>
#include <math.h>

#define N_NODES 32768
#define F 128
#define KD 64
#define M_NBR 32

__device__ __forceinline__ float ssp(float a) {
    // softplus(a) - log(2), numerically stable (matches jax.nn.softplus - log2)
    return fmaxf(a, 0.0f) + log1pf(expf(-fabsf(a))) - 0.69314718055994531f;
}

// ---------------------------------------------------------------------------
// Generic 128-col GEMM: out[r][c] = (+base[r][c]) (+u[c]*xin[r][c])
//                                   + act(A)[r][:] . W[c][:] + bias[c]
// A: [N,128], W: [128,128] row-major (we compute A @ W^T), 64 rows per block,
// 128 threads, each thread computes 8 rows x 8 cols (rows strided by 8,
// cols strided by 16 for LDS bank friendliness).
// ---------------------------------------------------------------------------
template<bool ACT_SSP, bool ADD_BASE, bool FINAL_UX>
__global__ __launch_bounds__(128)
void gemm128_kernel(const float* __restrict__ A, const float* __restrict__ W,
                    const float* __restrict__ bias, const float* __restrict__ base,
                    const float* __restrict__ xin, const float* __restrict__ u,
                    float* __restrict__ out)
{
    __shared__ float As[64][132];   // 64 rows x 128 k (pad 132: +4 -> bank spread)
    __shared__ float Ws[128][36];   // 128 cols x 32-k chunk (pad 36)

    const int t    = threadIdx.x;
    const int row0 = blockIdx.x * 64;

    // stage A tile (64x128 = 2048 float4), optional ssp
    {
        const float4* Ag = (const float4*)(A + (size_t)row0 * F);
        #pragma unroll
        for (int i = 0; i < 16; ++i) {
            int idx = i * 128 + t;
            int r = idx >> 5, seg = idx & 31;
            float4 v = Ag[idx];
            if (ACT_SSP) { v.x = ssp(v.x); v.y = ssp(v.y); v.z = ssp(v.z); v.w = ssp(v.w); }
            *(float4*)&As[r][seg * 4] = v;
        }
    }

    const int ty = t >> 4;   // 0..7  -> rows ty + 8*ri
    const int tx = t & 15;   // 0..15 -> cols tx + 16*ci

    float acc[8][8];
    #pragma unroll
    for (int i = 0; i < 8; ++i)
        #pragma unroll
        for (int j = 0; j < 8; ++j) acc[i][j] = 0.0f;

    for (int kk = 0; kk < 128; kk += 32) {
        __syncthreads();
        // stage W chunk: 128 cols x 32 k = 1024 float4
        #pragma unroll
        for (int i = 0; i < 8; ++i) {
            int idx = i * 128 + t;
            int c = idx >> 3, seg = idx & 7;
            float4 v = *(const float4*)(W + (size_t)c * F + kk + seg * 4);
            *(float4*)&Ws[c][seg * 4] = v;
        }
        __syncthreads();
        #pragma unroll
        for (int k4 = 0; k4 < 8; ++k4) {
            float4 a4[8], w4[8];
            #pragma unroll
            for (int ri = 0; ri < 8; ++ri)
                a4[ri] = *(const float4*)&As[ty + 8 * ri][kk + k4 * 4];
            #pragma unroll
            for (int ci = 0; ci < 8; ++ci)
                w4[ci] = *(const float4*)&Ws[tx + 16 * ci][k4 * 4];
            #pragma unroll
            for (int ri = 0; ri < 8; ++ri)
                #pragma unroll
                for (int ci = 0; ci < 8; ++ci) {
                    acc[ri][ci] = fmaf(a4[ri].x, w4[ci].x, acc[ri][ci]);
                    acc[ri][ci] = fmaf(a4[ri].y, w4[ci].y, acc[ri][ci]);
                    acc[ri][ci] = fmaf(a4[ri].z, w4[ci].z, acc[ri][ci]);
                    acc[ri][ci] = fmaf(a4[ri].w, w4[ci].w, acc[ri][ci]);
                }
        }
    }

    // epilogue
    #pragma unroll
    for (int ri = 0; ri < 8; ++ri) {
        int r = row0 + ty + 8 * ri;
        #pragma unroll
        for (int ci = 0; ci < 8; ++ci) {
            int c = tx + 16 * ci;
            float v = acc[ri][ci] + bias[c];
            if (ADD_BASE) v += base[(size_t)r * F + c];
            if (FINAL_UX) v += u[c] * xin[(size_t)r * F + c];
            out[(size_t)r * F + c] = v;
        }
    }
}

// ---------------------------------------------------------------------------
// Fused attention kernel: 4 nodes (=128 edges) per block, 256 threads.
//   g[e][c]  = sum_k rbf[e][k] * k2f[c][k]          (32x... 128x128x64 GEMM)
//   xj[e][c] = g[e][c] * xv[idx_j[e]][c]
//   s[n][m]  = sum_f xi[n][f] * xj[32n + f/4][(f%4)*32 + m]   (scrambled reshape)
//   att      = softmax_m(s)
//   m[n][f]  = xi[n][f] + sum_m att[m] * xj[32n+m][f]
// In-place: reads xi rows n0..n0+3 and writes m to the same rows.
// ---------------------------------------------------------------------------
__global__ __launch_bounds__(256)
void attn_kernel(const float* __restrict__ xi_in,   // [N,128] (= B0)
                 const float* __restrict__ xv,      // [N,128] (= B1)
                 const float* __restrict__ rbf,     // [E,64]
                 const int*   __restrict__ idx_j,   // [E]
                 const float* __restrict__ k2f,     // [128,64]
                 float* __restrict__ m_out)         // [N,128] (= B0, in-place)
{
    // Phase-1 region (rbf_s[128][68] + k2f_s[128][68]) is reused as xj_s[128][132]
    __shared__ float bufA[128 * 68 * 2];      // 69632 B
    __shared__ float xv_s[128][132];          // 67584 B
    __shared__ float xi_s[4][128];
    __shared__ float att_s[4][32];
    __shared__ int   idx_s[128];

    float* rbf_s = bufA;                 // [128][68]
    float* k2f_s = bufA + 128 * 68;      // [128][68]
    float* xj_s  = bufA;                 // [128][132] (after g-GEMM done)

    const int t  = threadIdx.x;
    const int blk = blockIdx.x;
    const int e0 = blk * 128;            // first edge of this block
    const int n0 = blk * 4;              // first node

    if (t < 128) idx_s[t] = idx_j[e0 + t];

    // stage rbf tile: 128 edges x 64 k = 2048 float4 (contiguous)
    {
        const float4* rg = (const float4*)(rbf + (size_t)e0 * KD);
        #pragma unroll
        for (int i = 0; i < 8; ++i) {
            int idx = i * 256 + t;
            int e = idx >> 4, seg = idx & 15;
            *(float4*)&rbf_s[e * 68 + seg * 4] = rg[idx];
        }
    }
    // stage k2f: 128 x 64 = 2048 float4
    {
        const float4* kg = (const float4*)k2f;
        #pragma unroll
        for (int i = 0; i < 8; ++i) {
            int idx = i * 256 + t;
            int c = idx >> 4, seg = idx & 15;
            *(float4*)&k2f_s[c * 68 + seg * 4] = kg[idx];
        }
    }
    // stage xi rows (4 x 128 = 128 float4)
    if (t < 128) {
        float4 v = ((const float4*)(xi_in + (size_t)n0 * F))[t];
        *(float4*)&xi_s[0][t * 4] = v;
    }
    __syncthreads();

    // gather xv rows via idx_j: 128 rows x 32 float4
    #pragma unroll
    for (int i = 0; i < 16; ++i) {
        int idx = i * 256 + t;
        int e = idx >> 5, seg = idx & 31;
        int j = idx_s[e];
        float4 v = *(const float4*)(xv + (size_t)j * F + seg * 4);
        *(float4*)&xv_s[e][seg * 4] = v;
    }

    // g-GEMM: thread (ty,tx) computes edges {ty+16*ei} x cols {tx+16*ci}, 8x8
    const int ty = t >> 4, tx = t & 15;
    float acc[8][8];
    #pragma unroll
    for (int i = 0; i < 8; ++i)
        #pragma unroll
        for (int j = 0; j < 8; ++j) acc[i][j] = 0.0f;

    #pragma unroll 4
    for (int k4 = 0; k4 < 16; ++k4) {
        float4 a4[8], b4[8];
        #pragma unroll
        for (int ei = 0; ei < 8; ++ei)
            a4[ei] = *(const float4*)&rbf_s[(ty + 16 * ei) * 68 + k4 * 4];
        #pragma unroll
        for (int ci = 0; ci < 8; ++ci)
            b4[ci] = *(const float4*)&k2f_s[(tx + 16 * ci) * 68 + k4 * 4];
        #pragma unroll
        for (int ei = 0; ei < 8; ++ei)
            #pragma unroll
            for (int ci = 0; ci < 8; ++ci) {
                acc[ei][ci] = fmaf(a4[ei].x, b4[ci].x, acc[ei][ci]);
                acc[ei][ci] = fmaf(a4[ei].y, b4[ci].y, acc[ei][ci]);
                acc[ei][ci] = fmaf(a4[ei].z, b4[ci].z, acc[ei][ci]);
                acc[ei][ci] = fmaf(a4[ei].w, b4[ci].w, acc[ei][ci]);
            }
    }
    __syncthreads();   // g done (rbf/k2f region free), xv_s gather complete

    // xj = g * xv  (overwrites phase-1 region)
    #pragma unroll
    for (int ei = 0; ei < 8; ++ei) {
        int e = ty + 16 * ei;
        #pragma unroll
        for (int ci = 0; ci < 8; ++ci) {
            int c = tx + 16 * ci;
            xj_s[e * 132 + c] = acc[ei][ci] * xv_s[e][c];
        }
    }
    __syncthreads();

    // logits + softmax: one thread per (node, m), t < 128
    if (t < 128) {
        int nn = t >> 5, m = t & 31;
        float s = 0.0f;
        #pragma unroll
        for (int f = 0; f < 128; ++f) {
            float xj = xj_s[(nn * 32 + (f >> 2)) * 132 + ((f & 3) * 32 + m)];
            s = fmaf(xi_s[nn][f], xj, s);
        }
        float mx = s;
        #pragma unroll
        for (int o = 16; o; o >>= 1) mx = fmaxf(mx, __shfl_xor(mx, o));
        float ex = expf(s - mx);
        float sum = ex;
        #pragma unroll
        for (int o = 16; o; o >>= 1) sum += __shfl_xor(sum, o);
        att_s[nn][m] = ex / sum;
    }
    __syncthreads();

    // output: m[n][f] = xi + sum_m att*xj ; 512 elems, 2 per thread
    #pragma unroll
    for (int i = 0; i < 2; ++i) {
        int idx = i * 256 + t;
        int nn = idx >> 7, f = idx & 127;
        float v = xi_s[nn][f];
        #pragma unroll
        for (int m = 0; m < 32; ++m)
            v = fmaf(att_s[nn][m], xj_s[(nn * 32 + m) * 132 + f], v);
        m_out[(size_t)(n0 + nn) * F + f] = v;
    }
}

// ---------------------------------------------------------------------------
extern "C" void kernel_launch(void* const* d_in, const int* in_sizes, int n_in,
                              void* d_out, int out_size, void* d_ws, size_t ws_size,
                              hipStream_t stream)
{
    const float* x     = (const float*)d_in[0];
    const float* rbf   = (const float*)d_in[1];
    // d_in[2] = idx_i : unused by the reference
    const int*   idx_j = (const int*)d_in[3];
    const float* k2f_w = (const float*)d_in[4];
    const float* wi    = (const float*)d_in[5];
    const float* bi    = (const float*)d_in[6];
    const float* wj    = (const float*)d_in[7];
    const float* bj    = (const float*)d_in[8];
    const float* rw1   = (const float*)d_in[9];
    const float* rb1   = (const float*)d_in[10];
    const float* rw2   = (const float*)d_in[11];
    const float* rb2   = (const float*)d_in[12];
    const float* wd    = (const float*)d_in[13];
    const float* bd    = (const float*)d_in[14];
    const float* u     = (const float*)d_in[15];
    float* out = (float*)d_out;

    const size_t NF = (size_t)N_NODES * F;
    float* B0 = (float*)d_ws;      // xi, then m (in-place)
    float* B1 = B0 + NF;           // xv
    float* B2 = B1 + NF;           // t (residual hidden)

    dim3 gb(N_NODES / 64), tb(128);

    // xi = ssp(x) @ wi^T + bi ; xv = ssp(x) @ wj^T + bj
    hipLaunchKernelGGL((gemm128_kernel<true, false, false>), gb, tb, 0, stream,
                       x, wi, bi, nullptr, nullptr, nullptr, B0);
    hipLaunchKernelGGL((gemm128_kernel<true, false, false>), gb, tb, 0, stream,
                       x, wj, bj, nullptr, nullptr, nullptr, B1);

    // fused rbf-GEMM + gather + attention -> m (in-place in B0)
    hipLaunchKernelGGL(attn_kernel, dim3(N_NODES / 4), dim3(256), 0, stream,
                       B0, B1, rbf, idx_j, k2f_w, B0);

    // residual block 0
    hipLaunchKernelGGL((gemm128_kernel<true, false, false>), gb, tb, 0, stream,
                       B0, rw1, rb1, nullptr, nullptr, nullptr, B2);
    hipLaunchKernelGGL((gemm128_kernel<false, true, false>), gb, tb, 0, stream,
                       B2, rw2, rb2, B0, nullptr, nullptr, B0);
    // residual block 1
    hipLaunchKernelGGL((gemm128_kernel<true, false, false>), gb, tb, 0, stream,
                       B0, rw1 + F * F, rb1 + F, nullptr, nullptr, nullptr, B2);
    hipLaunchKernelGGL((gemm128_kernel<false, true, false>), gb, tb, 0, stream,
                       B2, rw2 + F * F, rb2 + F, B0, nullptr, nullptr, B0);

    // out = u*x + ssp(m) @ wd^T + bd
    hipLaunchKernelGGL((gemm128_kernel<true, false, true>), gb, tb, 0, stream,
                       B0, wd, bd, nullptr, x, u, out);
}

// Round 2
// 910.288 us; speedup vs baseline: 1.0892x; 1.0892x over previous
//
#include <hip/hip_runtime.h>
#include <math.h>

#define N_NODES 32768
#define F 128
#define KD 64

__device__ __forceinline__ float ssp(float a) {
    // softplus(a) - log(2), numerically stable
    return fmaxf(a, 0.0f) + log1pf(expf(-fabsf(a))) - 0.69314718055994531f;
}

// ---------------------------------------------------------------------------
// Shared GEMM micro-kernel: acc[4][8] += src(LDS [32][132]) @ W^T (global,
// staged through Ws[128][36] in 32-k chunks). 128 threads; thread (ty,tx)
// owns rows {ty+8ri} x cols {tx+16ci}.
// ---------------------------------------------------------------------------
__device__ __forceinline__ void gemm_lds(const float (*__restrict__ src)[132],
                                         const float* __restrict__ W,
                                         float (*__restrict__ Ws)[36],
                                         float acc[4][8], int t, int ty, int tx)
{
    #pragma unroll
    for (int i = 0; i < 4; ++i)
        #pragma unroll
        for (int j = 0; j < 8; ++j) acc[i][j] = 0.0f;

    for (int kk = 0; kk < 128; kk += 32) {
        __syncthreads();   // protects prior Ws readers + prior src writes
        #pragma unroll
        for (int i = 0; i < 8; ++i) {
            int idx = i * 128 + t;
            int c = idx >> 3, seg = idx & 7;
            *(float4*)&Ws[c][seg * 4] = *(const float4*)(W + (size_t)c * F + kk + seg * 4);
        }
        __syncthreads();
        #pragma unroll
        for (int k4 = 0; k4 < 8; ++k4) {
            float4 a4[4], w4[8];
            #pragma unroll
            for (int ri = 0; ri < 4; ++ri)
                a4[ri] = *(const float4*)&src[ty + 8 * ri][kk + k4 * 4];
            #pragma unroll
            for (int ci = 0; ci < 8; ++ci)
                w4[ci] = *(const float4*)&Ws[tx + 16 * ci][k4 * 4];
            #pragma unroll
            for (int ri = 0; ri < 4; ++ri)
                #pragma unroll
                for (int ci = 0; ci < 8; ++ci) {
                    acc[ri][ci] = fmaf(a4[ri].x, w4[ci].x, acc[ri][ci]);
                    acc[ri][ci] = fmaf(a4[ri].y, w4[ci].y, acc[ri][ci]);
                    acc[ri][ci] = fmaf(a4[ri].z, w4[ci].z, acc[ri][ci]);
                    acc[ri][ci] = fmaf(a4[ri].w, w4[ci].w, acc[ri][ci]);
                }
        }
    }
}

// ---------------------------------------------------------------------------
// Input kernel: xi = ssp(x)@wi^T+bi ; xv = ssp(x)@wj^T+bj. A staged once.
// 32 rows/block, 128 threads, ~35 KB LDS -> 4 blocks/CU.
// ---------------------------------------------------------------------------
__global__ __launch_bounds__(128, 2)
void in_kernel(const float* __restrict__ x,
               const float* __restrict__ wi, const float* __restrict__ bi,
               const float* __restrict__ wj, const float* __restrict__ bj,
               float* __restrict__ xi_out, float* __restrict__ xv_out)
{
    __shared__ float As[32][132];
    __shared__ float Ws[128][36];
    const int t = threadIdx.x;
    const int row0 = blockIdx.x * 32;
    const int ty = t >> 4, tx = t & 15;

    {
        const float4* xg = (const float4*)(x + (size_t)row0 * F);
        #pragma unroll
        for (int i = 0; i < 8; ++i) {
            int idx = i * 128 + t;
            int r = idx >> 5, seg = idx & 31;
            float4 v = xg[idx];
            v.x = ssp(v.x); v.y = ssp(v.y); v.z = ssp(v.z); v.w = ssp(v.w);
            *(float4*)&As[r][seg * 4] = v;
        }
    }

    const float* Wp[2] = {wi, wj};
    const float* Bp[2] = {bi, bj};
    float* Op[2] = {xi_out, xv_out};
    #pragma unroll
    for (int w = 0; w < 2; ++w) {
        float acc[4][8];
        gemm_lds(As, Wp[w], Ws, acc, t, ty, tx);
        #pragma unroll
        for (int ri = 0; ri < 4; ++ri) {
            int r = row0 + ty + 8 * ri;
            #pragma unroll
            for (int ci = 0; ci < 8; ++ci) {
                int c = tx + 16 * ci;
                Op[w][(size_t)r * F + c] = acc[ri][ci] + Bp[w][c];
            }
        }
    }
}

// ---------------------------------------------------------------------------
// Fused attention: 4 nodes (128 edges)/block, 512 threads, ~72 KB LDS
// -> 2 blocks/CU (16 waves/CU). xv gathered straight into an in-place LDS
// multiply (no xv_s buffer). xj_s reuses the rbf/k2f region.
// ---------------------------------------------------------------------------
__global__ __launch_bounds__(512, 4)
void attn_kernel(const float* __restrict__ xi_in,   // [N,128]
                 const float* __restrict__ xv,      // [N,128]
                 const float* __restrict__ rbf,     // [E,64]
                 const int*   __restrict__ idx_j,   // [E]
                 const float* __restrict__ k2f,     // [128,64]
                 float* __restrict__ m_out)         // [N,128] (in-place ok)
{
    __shared__ float bufA[128 * 68 * 2];   // rbf_s[128][68] + k2f_s[128][68]; reused as xj_s[128][132]
    __shared__ float xi_s[4 * 128];
    __shared__ float att_s[4 * 32];
    __shared__ int   idx_s[128];
    float* rbf_s = bufA;
    float* k2f_s = bufA + 128 * 68;
    float* xj_s  = bufA;

    const int t  = threadIdx.x;
    const int e0 = blockIdx.x * 128;
    const int n0 = blockIdx.x * 4;

    if (t < 128) idx_s[t] = idx_j[e0 + t];
    {
        const float4* rg = (const float4*)(rbf + (size_t)e0 * KD);
        #pragma unroll
        for (int i = 0; i < 4; ++i) {
            int idx = i * 512 + t;
            int e = idx >> 4, seg = idx & 15;
            *(float4*)&rbf_s[e * 68 + seg * 4] = rg[idx];
        }
        const float4* kg = (const float4*)k2f;
        #pragma unroll
        for (int i = 0; i < 4; ++i) {
            int idx = i * 512 + t;
            int c = idx >> 4, seg = idx & 15;
            *(float4*)&k2f_s[c * 68 + seg * 4] = kg[idx];
        }
    }
    if (t < 128)
        *(float4*)&xi_s[t * 4] = ((const float4*)(xi_in + (size_t)n0 * F))[t];
    __syncthreads();

    // g-GEMM: thread (ty 0..31, tx 0..15) -> edges {ty+32ei}, cols {tx+16ci}
    const int ty = t >> 4, tx = t & 15;
    float acc[4][8];
    #pragma unroll
    for (int i = 0; i < 4; ++i)
        #pragma unroll
        for (int j = 0; j < 8; ++j) acc[i][j] = 0.0f;

    #pragma unroll 4
    for (int k4 = 0; k4 < 16; ++k4) {
        float4 a4[4], b4[8];
        #pragma unroll
        for (int ei = 0; ei < 4; ++ei)
            a4[ei] = *(const float4*)&rbf_s[(ty + 32 * ei) * 68 + k4 * 4];
        #pragma unroll
        for (int ci = 0; ci < 8; ++ci)
            b4[ci] = *(const float4*)&k2f_s[(tx + 16 * ci) * 68 + k4 * 4];
        #pragma unroll
        for (int ei = 0; ei < 4; ++ei)
            #pragma unroll
            for (int ci = 0; ci < 8; ++ci) {
                acc[ei][ci] = fmaf(a4[ei].x, b4[ci].x, acc[ei][ci]);
                acc[ei][ci] = fmaf(a4[ei].y, b4[ci].y, acc[ei][ci]);
                acc[ei][ci] = fmaf(a4[ei].z, b4[ci].z, acc[ei][ci]);
                acc[ei][ci] = fmaf(a4[ei].w, b4[ci].w, acc[ei][ci]);
            }
    }
    __syncthreads();   // rbf_s/k2f_s dead; acc holds g

    // write g into xj_s (reused region)
    #pragma unroll
    for (int ei = 0; ei < 4; ++ei) {
        int e = ty + 32 * ei;
        #pragma unroll
        for (int ci = 0; ci < 8; ++ci)
            xj_s[e * 132 + tx + 16 * ci] = acc[ei][ci];
    }
    __syncthreads();

    // gather xv rows and multiply in place: xj = g * xv[idx_j]
    #pragma unroll
    for (int i = 0; i < 8; ++i) {
        int idx = i * 512 + t;
        int e = idx >> 5, seg = idx & 31;
        int j = idx_s[e];
        float4 v = *(const float4*)(xv + (size_t)j * F + seg * 4);
        float* p = &xj_s[e * 132 + seg * 4];
        float4 g4 = *(float4*)p;
        g4.x *= v.x; g4.y *= v.y; g4.z *= v.z; g4.w *= v.w;
        *(float4*)p = g4;
    }
    __syncthreads();

    // logits + softmax (scrambled reshape), one thread per (node, m)
    if (t < 128) {
        int nn = t >> 5, m = t & 31;
        float s = 0.0f;
        #pragma unroll
        for (int f = 0; f < 128; ++f)
            s = fmaf(xi_s[nn * 128 + f],
                     xj_s[(nn * 32 + (f >> 2)) * 132 + (f & 3) * 32 + m], s);
        float mx = s;
        #pragma unroll
        for (int o = 16; o; o >>= 1) mx = fmaxf(mx, __shfl_xor(mx, o));
        float ex = expf(s - mx);
        float sum = ex;
        #pragma unroll
        for (int o = 16; o; o >>= 1) sum += __shfl_xor(sum, o);
        att_s[nn * 32 + m] = ex / sum;
    }
    __syncthreads();

    // output: m[n][f] = xi + sum_m att*xj[32n+m][f]; one elem per thread
    {
        int nn = t >> 7, f = t & 127;
        float v = xi_s[nn * 128 + f];
        #pragma unroll
        for (int m = 0; m < 32; ++m)
            v = fmaf(att_s[nn * 32 + m], xj_s[(nn * 32 + m) * 132 + f], v);
        m_out[(size_t)(n0 + nn) * F + f] = v;
    }
}

// ---------------------------------------------------------------------------
// Fused tail: both residual MLP blocks + final ssp + wd-GEMM + u*x + bd.
// Entirely row-local: 32 rows/block stay in LDS across all 5 GEMMs.
// ~52 KB LDS -> 3 blocks/CU. Weights (320 KB total) are L2-resident.
// ---------------------------------------------------------------------------
__global__ __launch_bounds__(128, 2)
void tail_kernel(const float* __restrict__ m_in, const float* __restrict__ x,
                 const float* __restrict__ u,
                 const float* __restrict__ rw1, const float* __restrict__ rb1,
                 const float* __restrict__ rw2, const float* __restrict__ rb2,
                 const float* __restrict__ wd, const float* __restrict__ bd,
                 float* __restrict__ out)
{
    __shared__ float cur[32][132];
    __shared__ float tmp[32][132];
    __shared__ float Ws[128][36];
    const int t = threadIdx.x;
    const int row0 = blockIdx.x * 32;
    const int ty = t >> 4, tx = t & 15;

    // load m rows
    {
        const float4* mg = (const float4*)(m_in + (size_t)row0 * F);
        #pragma unroll
        for (int i = 0; i < 8; ++i) {
            int idx = i * 128 + t;
            int r = idx >> 5, seg = idx & 31;
            *(float4*)&cur[r][seg * 4] = mg[idx];
        }
    }

    #pragma unroll 1
    for (int r = 0; r < 2; ++r) {
        __syncthreads();   // cur writes visible
        // tmp = ssp(cur)
        #pragma unroll
        for (int i = 0; i < 8; ++i) {
            int idx = i * 128 + t;
            int rr = idx >> 5, seg = idx & 31;
            float4 v = *(const float4*)&cur[rr][seg * 4];
            v.x = ssp(v.x); v.y = ssp(v.y); v.z = ssp(v.z); v.w = ssp(v.w);
            *(float4*)&tmp[rr][seg * 4] = v;
        }
        float acc[4][8];
        gemm_lds(tmp, rw1 + (size_t)r * F * F, Ws, acc, t, ty, tx);
        __syncthreads();   // all tmp reads done
        #pragma unroll
        for (int ri = 0; ri < 4; ++ri)
            #pragma unroll
            for (int ci = 0; ci < 8; ++ci) {
                int c = tx + 16 * ci;
                tmp[ty + 8 * ri][c] = acc[ri][ci] + rb1[r * F + c];
            }
        float acc2[4][8];
        gemm_lds(tmp, rw2 + (size_t)r * F * F, Ws, acc2, t, ty, tx);
        __syncthreads();
        #pragma unroll
        for (int ri = 0; ri < 4; ++ri)
            #pragma unroll
            for (int ci = 0; ci < 8; ++ci) {
                int c = tx + 16 * ci;
                cur[ty + 8 * ri][c] += acc2[ri][ci] + rb2[r * F + c];
            }
    }

    __syncthreads();
    // tmp = ssp(cur); final GEMM; out = u*x + tmp@wd^T + bd
    #pragma unroll
    for (int i = 0; i < 8; ++i) {
        int idx = i * 128 + t;
        int rr = idx >> 5, seg = idx & 31;
        float4 v = *(const float4*)&cur[rr][seg * 4];
        v.x = ssp(v.x); v.y = ssp(v.y); v.z = ssp(v.z); v.w = ssp(v.w);
        *(float4*)&tmp[rr][seg * 4] = v;
    }
    float acc[4][8];
    gemm_lds(tmp, wd, Ws, acc, t, ty, tx);
    #pragma unroll
    for (int ri = 0; ri < 4; ++ri) {
        int rr = row0 + ty + 8 * ri;
        #pragma unroll
        for (int ci = 0; ci < 8; ++ci) {
            int c = tx + 16 * ci;
            out[(size_t)rr * F + c] = fmaf(u[c], x[(size_t)rr * F + c], acc[ri][ci] + bd[c]);
        }
    }
}

// ---------------------------------------------------------------------------
extern "C" void kernel_launch(void* const* d_in, const int* in_sizes, int n_in,
                              void* d_out, int out_size, void* d_ws, size_t ws_size,
                              hipStream_t stream)
{
    const float* x     = (const float*)d_in[0];
    const float* rbf   = (const float*)d_in[1];
    const int*   idx_j = (const int*)d_in[3];   // idx_i (d_in[2]) unused by ref
    const float* k2f_w = (const float*)d_in[4];
    const float* wi    = (const float*)d_in[5];
    const float* bi    = (const float*)d_in[6];
    const float* wj    = (const float*)d_in[7];
    const float* bj    = (const float*)d_in[8];
    const float* rw1   = (const float*)d_in[9];
    const float* rb1   = (const float*)d_in[10];
    const float* rw2   = (const float*)d_in[11];
    const float* rb2   = (const float*)d_in[12];
    const float* wd    = (const float*)d_in[13];
    const float* bd    = (const float*)d_in[14];
    const float* u     = (const float*)d_in[15];
    float* out = (float*)d_out;

    const size_t NF = (size_t)N_NODES * F;
    float* B0 = (float*)d_ws;   // xi, then m (attn writes in place)
    float* B1 = B0 + NF;        // xv

    hipLaunchKernelGGL(in_kernel, dim3(N_NODES / 32), dim3(128), 0, stream,
                       x, wi, bi, wj, bj, B0, B1);

    hipLaunchKernelGGL(attn_kernel, dim3(N_NODES / 4), dim3(512), 0, stream,
                       B0, B1, rbf, idx_j, k2f_w, B0);

    hipLaunchKernelGGL(tail_kernel, dim3(N_NODES / 32), dim3(128), 0, stream,
                       B0, x, u, rw1, rb1, rw2, rb2, wd, bd, out);
}

// Round 3
// 618.992 us; speedup vs baseline: 1.6018x; 1.4706x over previous
//
#include <hip/hip_runtime.h>
#include <math.h>

#define N_NODES 32768
#define F 128
#define KD 64

typedef short  s8v  __attribute__((ext_vector_type(8)));   // 8 x bf16 (bit pattern)
typedef float  f4v  __attribute__((ext_vector_type(4)));   // MFMA accumulator
typedef unsigned short u16;

__device__ __forceinline__ float ssp(float a) {
    return fmaxf(a, 0.0f) + log1pf(expf(-fabsf(a))) - 0.69314718055994531f;
}
__device__ __forceinline__ u16 f2b(float f) {               // fp32 -> bf16 RNE
    unsigned int u = __builtin_bit_cast(unsigned int, f);
    u += 0x7fffu + ((u >> 16) & 1u);
    return (u16)(u >> 16);
}
__device__ __forceinline__ float b2f(u16 h) {
    unsigned int u = ((unsigned int)h) << 16;
    return __builtin_bit_cast(float, u);
}

// ---------------------------------------------------------------------------
// MFMA GEMM core: rows 64 (A in LDS, [64][136] bf16), cols 128, K=128.
// B-fragments read DIRECTLY from global bf16 weights [128 cols][128 k]
// (L1/L2-resident). Wave w owns rows w*16..w*16+15; acc[ct] = 16x16 tile ct.
// A-frag: lane(m=lane&15,q=lane>>4) holds A[w*16+m][ks*32+q*8 .. +8].
// C/D: col=lane&15, row=q*4+reg.
// ---------------------------------------------------------------------------
__device__ __forceinline__ void mfma_gemm64(const u16* A_b, const u16* Wg,
                                            int w, int m, int q, f4v acc[8])
{
    #pragma unroll
    for (int ct = 0; ct < 8; ++ct) acc[ct] = (f4v){0.f, 0.f, 0.f, 0.f};
    #pragma unroll
    for (int ks = 0; ks < 4; ++ks) {
        s8v a = *(const s8v*)&A_b[(w * 16 + m) * 136 + ks * 32 + q * 8];
        #pragma unroll
        for (int ct = 0; ct < 8; ++ct) {
            s8v b = *(const s8v*)&Wg[(ct * 16 + m) * 128 + ks * 32 + q * 8];
            acc[ct] = __builtin_amdgcn_mfma_f32_16x16x32_bf16(a, b, acc[ct], 0, 0, 0);
        }
    }
}

__device__ __forceinline__ void writeA(u16* A_b, int w, int q, int m, const float v[8][4])
{
    #pragma unroll
    for (int ct = 0; ct < 8; ++ct) {
        int c = ct * 16 + m;
        #pragma unroll
        for (int reg = 0; reg < 4; ++reg)
            A_b[(w * 16 + q * 4 + reg) * 136 + c] = f2b(v[ct][reg]);
    }
}

// ---------------------------------------------------------------------------
// prep: fp32 -> bf16 for 7 weight matrices (wi,wj,rw1_0,rw2_0,rw1_1,rw2_1,wd)
// and k2f. 120 blocks x 256 thr x 4 elems.
// ---------------------------------------------------------------------------
__global__ __launch_bounds__(256)
void prep_kernel(const float* __restrict__ wi, const float* __restrict__ wj,
                 const float* __restrict__ rw1, const float* __restrict__ rw2,
                 const float* __restrict__ wd, const float* __restrict__ k2f,
                 u16* __restrict__ WB, u16* __restrict__ K2FB)
{
    int b = blockIdx.x, t = threadIdx.x;
    const float* src; u16* dst; int off;
    if (b < 112) {
        int seg = b >> 4; off = (b & 15) * 1024 + t * 4;
        const float* srcs[7] = {wi, wj, rw1, rw2, rw1 + 16384, rw2 + 16384, wd};
        src = srcs[seg]; dst = WB + seg * 16384;
    } else {
        off = (b - 112) * 1024 + t * 4;
        src = k2f; dst = K2FB;
    }
    float4 v = *(const float4*)(src + off);
    ushort4 h; h.x = f2b(v.x); h.y = f2b(v.y); h.z = f2b(v.z); h.w = f2b(v.w);
    *(ushort4*)(dst + off) = h;
}

// ---------------------------------------------------------------------------
// in: xi = ssp(x)@wi^T+bi (fp32 out) ; xv = ssp(x)@wj^T+bj (bf16 out).
// 64 rows/block, 256 thr, LDS = A_b only (17.4 KB), one barrier.
// ---------------------------------------------------------------------------
__global__ __launch_bounds__(256, 4)
void in_kernel(const float* __restrict__ x, const u16* __restrict__ WB,
               const float* __restrict__ bi, const float* __restrict__ bj,
               float* __restrict__ xi_out, u16* __restrict__ xv_out)
{
    __shared__ u16 A_b[64 * 136];
    const int t = threadIdx.x, row0 = blockIdx.x * 64;
    const int w = t >> 6, lane = t & 63, m = lane & 15, q = lane >> 4;

    {   // stage A = bf16(ssp(x)) : coalesced float4 reads, b64 LDS writes
        const float4* xg = (const float4*)(x + (size_t)row0 * F);
        #pragma unroll
        for (int i = 0; i < 8; ++i) {
            int idx = i * 256 + t, r = idx >> 5, seg = idx & 31;
            float4 v = xg[idx];
            ushort4 h;
            h.x = f2b(ssp(v.x)); h.y = f2b(ssp(v.y));
            h.z = f2b(ssp(v.z)); h.w = f2b(ssp(v.w));
            *(ushort4*)&A_b[r * 136 + seg * 4] = h;
        }
    }
    __syncthreads();

    f4v acc[8];
    mfma_gemm64(A_b, WB + 0 * 16384, w, m, q, acc);     // wi
    #pragma unroll
    for (int ct = 0; ct < 8; ++ct) {
        int c = ct * 16 + m; float bv = bi[c];
        #pragma unroll
        for (int reg = 0; reg < 4; ++reg) {
            int r = row0 + w * 16 + q * 4 + reg;
            xi_out[(size_t)r * F + c] = acc[ct][reg] + bv;
        }
    }
    mfma_gemm64(A_b, WB + 1 * 16384, w, m, q, acc);     // wj (A_b unchanged)
    #pragma unroll
    for (int ct = 0; ct < 8; ++ct) {
        int c = ct * 16 + m; float bv = bj[c];
        #pragma unroll
        for (int reg = 0; reg < 4; ++reg) {
            int r = row0 + w * 16 + q * 4 + reg;
            xv_out[(size_t)r * F + c] = f2b(acc[ct][reg] + bv);
        }
    }
}

// ---------------------------------------------------------------------------
// attn: g = rbf@k2f^T via MFMA (A-frags straight from global rbf, B-frags
// from global bf16 k2f), xj = g*xv[idx_j] (bf16 in LDS), scrambled-reshape
// softmax attention, m = xi + att.xj. 4 nodes (128 edges)/block, 512 thr,
// LDS 38 KB -> up to 4 blocks/CU.
// ---------------------------------------------------------------------------
__global__ __launch_bounds__(512, 4)
void attn_kernel(const float* __restrict__ xi_in, const u16* __restrict__ xvb,
                 const float* __restrict__ rbf, const int* __restrict__ idx_j,
                 const u16* __restrict__ k2fb, float* __restrict__ m_out)
{
    __shared__ u16   xj_s[128 * 136];
    __shared__ float xi_s[512];
    __shared__ float att_s[128];
    __shared__ int   idx_s[128];

    const int t = threadIdx.x;
    const size_t e0 = (size_t)blockIdx.x * 128;
    const int n0 = blockIdx.x * 4;

    if (t < 128) {
        idx_s[t] = idx_j[e0 + t];
        ((float4*)xi_s)[t] = ((const float4*)(xi_in + (size_t)n0 * F))[t];
    }

    const int w = t >> 6, lane = t & 63, m = lane & 15, q = lane >> 4;

    // ---- g-GEMM: 128 edges x 128 cols x K=64
    f4v acc[8];
    #pragma unroll
    for (int ct = 0; ct < 8; ++ct) acc[ct] = (f4v){0.f, 0.f, 0.f, 0.f};
    const float* arow = rbf + (e0 + (size_t)(w * 16 + m)) * KD;
    #pragma unroll
    for (int ks = 0; ks < 2; ++ks) {
        float4 a0 = *(const float4*)(arow + ks * 32 + q * 8);
        float4 a1 = *(const float4*)(arow + ks * 32 + q * 8 + 4);
        s8v a;
        a[0] = (short)f2b(a0.x); a[1] = (short)f2b(a0.y);
        a[2] = (short)f2b(a0.z); a[3] = (short)f2b(a0.w);
        a[4] = (short)f2b(a1.x); a[5] = (short)f2b(a1.y);
        a[6] = (short)f2b(a1.z); a[7] = (short)f2b(a1.w);
        #pragma unroll
        for (int ct = 0; ct < 8; ++ct) {
            s8v b = *(const s8v*)&k2fb[(ct * 16 + m) * KD + ks * 32 + q * 8];
            acc[ct] = __builtin_amdgcn_mfma_f32_16x16x32_bf16(a, b, acc[ct], 0, 0, 0);
        }
    }
    // g -> xj_s (bf16)
    #pragma unroll
    for (int ct = 0; ct < 8; ++ct) {
        int c = ct * 16 + m;
        #pragma unroll
        for (int reg = 0; reg < 4; ++reg)
            xj_s[(w * 16 + q * 4 + reg) * 136 + c] = f2b(acc[ct][reg]);
    }
    __syncthreads();

    // ---- xj *= xv[idx_j[e]] : 4 threads per edge, b128 RMW
    {
        int e = t >> 2, coff = (t & 3) * 32;
        size_t j = (size_t)idx_s[e];
        #pragma unroll
        for (int i = 0; i < 4; ++i) {
            s8v xv8 = *(const s8v*)&xvb[j * F + coff + i * 8];
            u16* p = &xj_s[e * 136 + coff + i * 8];
            s8v g8 = *(const s8v*)p;
            s8v r;
            #pragma unroll
            for (int k = 0; k < 8; ++k)
                r[k] = (short)f2b(b2f((u16)g8[k]) * b2f((u16)xv8[k]));
            *(s8v*)p = r;
        }
    }
    __syncthreads();

    // ---- logits (scrambled reshape) + softmax, one thread per (node, m)
    if (t < 128) {
        int nn = t >> 5, mm = t & 31;
        float s = 0.f;
        #pragma unroll
        for (int f = 0; f < 128; ++f)
            s = fmaf(xi_s[nn * 128 + f],
                     b2f(xj_s[(nn * 32 + (f >> 2)) * 136 + (f & 3) * 32 + mm]), s);
        float mx = s;
        #pragma unroll
        for (int o = 16; o; o >>= 1) mx = fmaxf(mx, __shfl_xor(mx, o));
        float ex = expf(s - mx);
        float sum = ex;
        #pragma unroll
        for (int o = 16; o; o >>= 1) sum += __shfl_xor(sum, o);
        att_s[nn * 32 + mm] = ex / sum;
    }
    __syncthreads();

    // ---- m[n][f] = xi + sum_m att*xj[32n+m][f] ; coalesced store
    {
        int nn = t >> 7, f = t & 127;
        float v = xi_s[nn * 128 + f];
        #pragma unroll
        for (int mm = 0; mm < 32; ++mm)
            v = fmaf(att_s[nn * 32 + mm], b2f(xj_s[(nn * 32 + mm) * 136 + f]), v);
        m_out[(size_t)(n0 + nn) * F + f] = v;
    }
}

// ---------------------------------------------------------------------------
// tail: 2 residual MLP blocks + final ssp/wd/u*x/bd. Running m held in
// C-layout registers; LDS only for the C->A layout round-trip (17.4 KB).
// ---------------------------------------------------------------------------
__global__ __launch_bounds__(256, 3)
void tail_kernel(const float* __restrict__ m_in, const float* __restrict__ x,
                 const float* __restrict__ u, const u16* __restrict__ WB,
                 const float* __restrict__ rb1, const float* __restrict__ rb2,
                 const float* __restrict__ bd, float* __restrict__ out)
{
    __shared__ u16 A_b[64 * 136];
    const int t = threadIdx.x, row0 = blockIdx.x * 64;
    const int w = t >> 6, lane = t & 63, m = lane & 15, q = lane >> 4;
    const int rbase = row0 + w * 16 + q * 4;

    float cur[8][4], tmp[8][4];
    #pragma unroll
    for (int ct = 0; ct < 8; ++ct) {
        int c = ct * 16 + m;
        #pragma unroll
        for (int reg = 0; reg < 4; ++reg)
            cur[ct][reg] = m_in[(size_t)(rbase + reg) * F + c];
    }

    f4v acc[8];
    #pragma unroll 1
    for (int r = 0; r < 2; ++r) {
        // y = ssp(cur) -> A
        #pragma unroll
        for (int ct = 0; ct < 8; ++ct)
            #pragma unroll
            for (int reg = 0; reg < 4; ++reg) tmp[ct][reg] = ssp(cur[ct][reg]);
        writeA(A_b, w, q, m, tmp);
        __syncthreads();
        mfma_gemm64(A_b, WB + (2 + 2 * r) * 16384, w, m, q, acc);   // rw1_r
        __syncthreads();
        // h = acc + rb1_r -> A
        #pragma unroll
        for (int ct = 0; ct < 8; ++ct) {
            float bv = rb1[r * F + ct * 16 + m];
            #pragma unroll
            for (int reg = 0; reg < 4; ++reg) tmp[ct][reg] = acc[ct][reg] + bv;
        }
        writeA(A_b, w, q, m, tmp);
        __syncthreads();
        mfma_gemm64(A_b, WB + (3 + 2 * r) * 16384, w, m, q, acc);   // rw2_r
        #pragma unroll
        for (int ct = 0; ct < 8; ++ct) {
            float bv = rb2[r * F + ct * 16 + m];
            #pragma unroll
            for (int reg = 0; reg < 4; ++reg) cur[ct][reg] += acc[ct][reg] + bv;
        }
        __syncthreads();   // guard A_b overwrite next iteration
    }

    // final: ssp -> wd -> u*x + bd
    #pragma unroll
    for (int ct = 0; ct < 8; ++ct)
        #pragma unroll
        for (int reg = 0; reg < 4; ++reg) tmp[ct][reg] = ssp(cur[ct][reg]);
    writeA(A_b, w, q, m, tmp);
    __syncthreads();
    mfma_gemm64(A_b, WB + 6 * 16384, w, m, q, acc);                 // wd
    #pragma unroll
    for (int ct = 0; ct < 8; ++ct) {
        int c = ct * 16 + m;
        float uv = u[c], bv = bd[c];
        #pragma unroll
        for (int reg = 0; reg < 4; ++reg) {
            size_t r = (size_t)(rbase + reg) * F + c;
            out[r] = fmaf(uv, x[r], acc[ct][reg] + bv);
        }
    }
}

// ---------------------------------------------------------------------------
extern "C" void kernel_launch(void* const* d_in, const int* in_sizes, int n_in,
                              void* d_out, int out_size, void* d_ws, size_t ws_size,
                              hipStream_t stream)
{
    const float* x     = (const float*)d_in[0];
    const float* rbf   = (const float*)d_in[1];
    const int*   idx_j = (const int*)d_in[3];   // idx_i (d_in[2]) unused by ref
    const float* k2f_w = (const float*)d_in[4];
    const float* wi    = (const float*)d_in[5];
    const float* bi    = (const float*)d_in[6];
    const float* wj    = (const float*)d_in[7];
    const float* bj    = (const float*)d_in[8];
    const float* rw1   = (const float*)d_in[9];
    const float* rb1   = (const float*)d_in[10];
    const float* rw2   = (const float*)d_in[11];
    const float* rb2   = (const float*)d_in[12];
    const float* wd    = (const float*)d_in[13];
    const float* bd    = (const float*)d_in[14];
    const float* u     = (const float*)d_in[15];
    float* out = (float*)d_out;

    const size_t NF = (size_t)N_NODES * F;
    float* B0   = (float*)d_ws;          // xi, then m (attn writes in place)
    u16*   XVB  = (u16*)(B0 + NF);       // xv bf16
    u16*   WB   = XVB + NF;              // 7 x [128][128] bf16 weights
    u16*   K2FB = WB + 7 * 16384;        // [128][64] bf16

    hipLaunchKernelGGL(prep_kernel, dim3(120), dim3(256), 0, stream,
                       wi, wj, rw1, rw2, wd, k2f_w, WB, K2FB);

    hipLaunchKernelGGL(in_kernel, dim3(N_NODES / 64), dim3(256), 0, stream,
                       x, WB, bi, bj, B0, XVB);

    hipLaunchKernelGGL(attn_kernel, dim3(N_NODES / 4), dim3(512), 0, stream,
                       B0, XVB, rbf, idx_j, K2FB, B0);

    hipLaunchKernelGGL(tail_kernel, dim3(N_NODES / 64), dim3(256), 0, stream,
                       B0, x, u, WB, rb1, rb2, bd, out);
}

// Round 4
// 591.427 us; speedup vs baseline: 1.6764x; 1.0466x over previous
//
#include <hip/hip_runtime.h>
#include <math.h>

#define N_NODES 32768
#define F 128
#define KD 64

typedef short  s8v  __attribute__((ext_vector_type(8)));   // 8 x bf16 (bit pattern)
typedef float  f4v  __attribute__((ext_vector_type(4)));   // MFMA accumulator
typedef unsigned short u16;

__device__ __forceinline__ float ssp(float a) {
    return fmaxf(a, 0.0f) + log1pf(expf(-fabsf(a))) - 0.69314718055994531f;
}
__device__ __forceinline__ u16 f2b(float f) {               // fp32 -> bf16 RNE
    unsigned int u = __builtin_bit_cast(unsigned int, f);
    u += 0x7fffu + ((u >> 16) & 1u);
    return (u16)(u >> 16);
}
__device__ __forceinline__ float b2f(u16 h) {
    unsigned int u = ((unsigned int)h) << 16;
    return __builtin_bit_cast(float, u);
}

// ---------------------------------------------------------------------------
// MFMA GEMM core: 64 rows (A in LDS [64][136] bf16) x 128 cols x K=128.
// B-frags direct from global bf16 weights (L1-resident, shared by all waves).
// Wave w owns rows w*16..w*16+15. C/D: col=lane&15, row=(lane>>4)*4+reg.
// ---------------------------------------------------------------------------
__device__ __forceinline__ void mfma_gemm64(const u16* A_b, const u16* Wg,
                                            int w, int m, int q, f4v acc[8])
{
    #pragma unroll
    for (int ct = 0; ct < 8; ++ct) acc[ct] = (f4v){0.f, 0.f, 0.f, 0.f};
    #pragma unroll
    for (int ks = 0; ks < 4; ++ks) {
        s8v a = *(const s8v*)&A_b[(w * 16 + m) * 136 + ks * 32 + q * 8];
        #pragma unroll
        for (int ct = 0; ct < 8; ++ct) {
            s8v b = *(const s8v*)&Wg[(ct * 16 + m) * 128 + ks * 32 + q * 8];
            acc[ct] = __builtin_amdgcn_mfma_f32_16x16x32_bf16(a, b, acc[ct], 0, 0, 0);
        }
    }
}

__device__ __forceinline__ void writeA(u16* A_b, int w, int q, int m, const float v[8][4])
{
    #pragma unroll
    for (int ct = 0; ct < 8; ++ct) {
        int c = ct * 16 + m;
        #pragma unroll
        for (int reg = 0; reg < 4; ++reg)
            A_b[(w * 16 + q * 4 + reg) * 136 + c] = f2b(v[ct][reg]);
    }
}

// ---------------------------------------------------------------------------
// prep: fp32 -> bf16 for weights + k2f.
// ---------------------------------------------------------------------------
__global__ __launch_bounds__(256)
void prep_kernel(const float* __restrict__ wi, const float* __restrict__ wj,
                 const float* __restrict__ rw1, const float* __restrict__ rw2,
                 const float* __restrict__ wd, const float* __restrict__ k2f,
                 u16* __restrict__ WB, u16* __restrict__ K2FB)
{
    int b = blockIdx.x, t = threadIdx.x;
    const float* src; u16* dst; int off;
    if (b < 112) {
        int seg = b >> 4; off = (b & 15) * 1024 + t * 4;
        const float* srcs[7] = {wi, wj, rw1, rw2, rw1 + 16384, rw2 + 16384, wd};
        src = srcs[seg]; dst = WB + seg * 16384;
    } else {
        off = (b - 112) * 1024 + t * 4;
        src = k2f; dst = K2FB;
    }
    float4 v = *(const float4*)(src + off);
    ushort4 h; h.x = f2b(v.x); h.y = f2b(v.y); h.z = f2b(v.z); h.w = f2b(v.w);
    *(ushort4*)(dst + off) = h;
}

// ---------------------------------------------------------------------------
// in: xi = ssp(x)@wi^T+bi (fp32, scatter 64B-segment stores) ;
//     xv = ssp(x)@wj^T+bj (bf16, coalesced via LDS restage).
// ---------------------------------------------------------------------------
__global__ __launch_bounds__(256, 4)
void in_kernel(const float* __restrict__ x, const u16* __restrict__ WB,
               const float* __restrict__ bi, const float* __restrict__ bj,
               float* __restrict__ xi_out, u16* __restrict__ xv_out)
{
    __shared__ u16 A_b[64 * 136];
    const int t = threadIdx.x, row0 = blockIdx.x * 64;
    const int w = t >> 6, lane = t & 63, m = lane & 15, q = lane >> 4;

    {   // stage A = bf16(ssp(x))
        const float4* xg = (const float4*)(x + (size_t)row0 * F);
        #pragma unroll
        for (int i = 0; i < 8; ++i) {
            int idx = i * 256 + t, r = idx >> 5, seg = idx & 31;
            float4 v = xg[idx];
            ushort4 h;
            h.x = f2b(ssp(v.x)); h.y = f2b(ssp(v.y));
            h.z = f2b(ssp(v.z)); h.w = f2b(ssp(v.w));
            *(ushort4*)&A_b[r * 136 + seg * 4] = h;
        }
    }
    __syncthreads();

    f4v acc[8];
    mfma_gemm64(A_b, WB + 0 * 16384, w, m, q, acc);     // wi
    #pragma unroll
    for (int ct = 0; ct < 8; ++ct) {
        int c = ct * 16 + m; float bv = bi[c];
        #pragma unroll
        for (int reg = 0; reg < 4; ++reg) {
            int r = row0 + w * 16 + q * 4 + reg;
            xi_out[(size_t)r * F + c] = acc[ct][reg] + bv;
        }
    }
    mfma_gemm64(A_b, WB + 1 * 16384, w, m, q, acc);     // wj
    __syncthreads();   // all A_b reads done; reuse A_b for xv staging
    #pragma unroll
    for (int ct = 0; ct < 8; ++ct) {
        int c = ct * 16 + m; float bv = bj[c];
        #pragma unroll
        for (int reg = 0; reg < 4; ++reg)
            A_b[(w * 16 + q * 4 + reg) * 136 + c] = f2b(acc[ct][reg] + bv);
    }
    __syncthreads();
    {   // coalesced bf16 stores: 64 rows x 128 cols
        u16* dst = xv_out + (size_t)row0 * F;
        #pragma unroll
        for (int i = 0; i < 8; ++i) {
            int idx = i * 256 + t, r = idx >> 5, seg = idx & 31;
            *(ushort4*)&dst[r * F + seg * 4] = *(const ushort4*)&A_b[r * 136 + seg * 4];
        }
    }
}

// ---------------------------------------------------------------------------
// attn: 2 nodes (64 edges)/block, 256 thr, ~19 KB LDS -> many blocks/CU.
// xv gather prefetched to registers BEFORE g-MFMA (latency overlap, no idx
// barrier). Logits phase uses all 256 threads (4-way f-split).
// ---------------------------------------------------------------------------
__global__ __launch_bounds__(256, 4)
void attn_kernel(const float* __restrict__ xi_in, const u16* __restrict__ xvb,
                 const float* __restrict__ rbf, const int* __restrict__ idx_j,
                 const u16* __restrict__ k2fb, float* __restrict__ m_out)
{
    __shared__ u16   xj_s[64 * 136];     // 17408 B
    __shared__ float xi_s[2 * 128];
    __shared__ float red_s[2][2][32];
    __shared__ float att_s[2 * 32];

    const int t = threadIdx.x;
    const size_t e0 = (size_t)blockIdx.x * 64;
    const int n0 = blockIdx.x * 2;

    // ---- prefetch xv[idx_j] straight into registers (no barrier needed)
    const int e_my = t >> 2, coff = (t & 3) * 32;
    const int jj = idx_j[e0 + e_my];
    s8v xv_r[4];
    #pragma unroll
    for (int i = 0; i < 4; ++i)
        xv_r[i] = *(const s8v*)&xvb[(size_t)jj * F + coff + i * 8];

    if (t < 64)
        ((float4*)xi_s)[t] = ((const float4*)(xi_in + (size_t)n0 * F))[t];

    // ---- g-GEMM: 64 edges x 128 cols x K=64 (overlaps gather latency)
    const int w = t >> 6, lane = t & 63, m = lane & 15, q = lane >> 4;
    f4v acc[8];
    #pragma unroll
    for (int ct = 0; ct < 8; ++ct) acc[ct] = (f4v){0.f, 0.f, 0.f, 0.f};
    const float* arow = rbf + (e0 + (size_t)(w * 16 + m)) * KD;
    #pragma unroll
    for (int ks = 0; ks < 2; ++ks) {
        float4 a0 = *(const float4*)(arow + ks * 32 + q * 8);
        float4 a1 = *(const float4*)(arow + ks * 32 + q * 8 + 4);
        s8v a;
        a[0] = (short)f2b(a0.x); a[1] = (short)f2b(a0.y);
        a[2] = (short)f2b(a0.z); a[3] = (short)f2b(a0.w);
        a[4] = (short)f2b(a1.x); a[5] = (short)f2b(a1.y);
        a[6] = (short)f2b(a1.z); a[7] = (short)f2b(a1.w);
        #pragma unroll
        for (int ct = 0; ct < 8; ++ct) {
            s8v b = *(const s8v*)&k2fb[(ct * 16 + m) * KD + ks * 32 + q * 8];
            acc[ct] = __builtin_amdgcn_mfma_f32_16x16x32_bf16(a, b, acc[ct], 0, 0, 0);
        }
    }
    // g -> xj_s (bf16, C-layout scatter)
    #pragma unroll
    for (int ct = 0; ct < 8; ++ct) {
        int c = ct * 16 + m;
        #pragma unroll
        for (int reg = 0; reg < 4; ++reg)
            xj_s[(w * 16 + q * 4 + reg) * 136 + c] = f2b(acc[ct][reg]);
    }
    __syncthreads();

    // ---- xj *= xv (prefetched): 4 threads/edge, b128 RMW
    #pragma unroll
    for (int i = 0; i < 4; ++i) {
        u16* p = &xj_s[e_my * 136 + coff + i * 8];
        s8v g8 = *(const s8v*)p;
        s8v r;
        #pragma unroll
        for (int k = 0; k < 8; ++k)
            r[k] = (short)f2b(b2f((u16)g8[k]) * b2f((u16)xv_r[i][k]));
        *(s8v*)p = r;
    }
    __syncthreads();

    // ---- logits: all 256 threads; t = (nn, part, mm)
    {
        const int nn = t >> 7, part = (t >> 5) & 3, mm = t & 31;
        float s = 0.f;
        #pragma unroll
        for (int fo = 0; fo < 32; ++fo) {
            int f = part * 32 + fo;
            s = fmaf(xi_s[nn * 128 + f],
                     b2f(xj_s[(nn * 32 + (f >> 2)) * 136 + (f & 3) * 32 + mm]), s);
        }
        s += __shfl_xor(s, 32);          // combine part pairs within wave
        if (lane < 32) red_s[nn][w & 1][mm] = s;
    }
    __syncthreads();
    if (t < 64) {
        const int nn = t >> 5, mm = t & 31;
        float s = red_s[nn][0][mm] + red_s[nn][1][mm];
        float mx = s;
        #pragma unroll
        for (int o = 16; o; o >>= 1) mx = fmaxf(mx, __shfl_xor(mx, o));
        float ex = expf(s - mx);
        float sum = ex;
        #pragma unroll
        for (int o = 16; o; o >>= 1) sum += __shfl_xor(sum, o);
        att_s[nn * 32 + mm] = ex / sum;
    }
    __syncthreads();

    // ---- m[n][f] = xi + sum_m att*xj[32n+m][f] ; coalesced fp32 store
    {
        const int nn = t >> 7, f = t & 127;
        float v = xi_s[nn * 128 + f];
        #pragma unroll
        for (int mm = 0; mm < 32; ++mm)
            v = fmaf(att_s[nn * 32 + mm], b2f(xj_s[(nn * 32 + mm) * 136 + f]), v);
        m_out[(size_t)(n0 + nn) * F + f] = v;
    }
}

// ---------------------------------------------------------------------------
// tail: 2 residual MLP blocks + final ssp/wd/u*x/bd; m in C-layout registers.
// ---------------------------------------------------------------------------
__global__ __launch_bounds__(256, 3)
void tail_kernel(const float* __restrict__ m_in, const float* __restrict__ x,
                 const float* __restrict__ u, const u16* __restrict__ WB,
                 const float* __restrict__ rb1, const float* __restrict__ rb2,
                 const float* __restrict__ bd, float* __restrict__ out)
{
    __shared__ u16 A_b[64 * 136];
    const int t = threadIdx.x, row0 = blockIdx.x * 64;
    const int w = t >> 6, lane = t & 63, m = lane & 15, q = lane >> 4;
    const int rbase = row0 + w * 16 + q * 4;

    float cur[8][4], tmp[8][4];
    #pragma unroll
    for (int ct = 0; ct < 8; ++ct) {
        int c = ct * 16 + m;
        #pragma unroll
        for (int reg = 0; reg < 4; ++reg)
            cur[ct][reg] = m_in[(size_t)(rbase + reg) * F + c];
    }

    f4v acc[8];
    #pragma unroll 1
    for (int r = 0; r < 2; ++r) {
        #pragma unroll
        for (int ct = 0; ct < 8; ++ct)
            #pragma unroll
            for (int reg = 0; reg < 4; ++reg) tmp[ct][reg] = ssp(cur[ct][reg]);
        writeA(A_b, w, q, m, tmp);
        __syncthreads();
        mfma_gemm64(A_b, WB + (2 + 2 * r) * 16384, w, m, q, acc);   // rw1_r
        __syncthreads();
        #pragma unroll
        for (int ct = 0; ct < 8; ++ct) {
            float bv = rb1[r * F + ct * 16 + m];
            #pragma unroll
            for (int reg = 0; reg < 4; ++reg) tmp[ct][reg] = acc[ct][reg] + bv;
        }
        writeA(A_b, w, q, m, tmp);
        __syncthreads();
        mfma_gemm64(A_b, WB + (3 + 2 * r) * 16384, w, m, q, acc);   // rw2_r
        #pragma unroll
        for (int ct = 0; ct < 8; ++ct) {
            float bv = rb2[r * F + ct * 16 + m];
            #pragma unroll
            for (int reg = 0; reg < 4; ++reg) cur[ct][reg] += acc[ct][reg] + bv;
        }
        __syncthreads();
    }

    #pragma unroll
    for (int ct = 0; ct < 8; ++ct)
        #pragma unroll
        for (int reg = 0; reg < 4; ++reg) tmp[ct][reg] = ssp(cur[ct][reg]);
    writeA(A_b, w, q, m, tmp);
    __syncthreads();
    mfma_gemm64(A_b, WB + 6 * 16384, w, m, q, acc);                 // wd
    #pragma unroll
    for (int ct = 0; ct < 8; ++ct) {
        int c = ct * 16 + m;
        float uv = u[c], bv = bd[c];
        #pragma unroll
        for (int reg = 0; reg < 4; ++reg) {
            size_t r = (size_t)(rbase + reg) * F + c;
            out[r] = fmaf(uv, x[r], acc[ct][reg] + bv);
        }
    }
}

// ---------------------------------------------------------------------------
extern "C" void kernel_launch(void* const* d_in, const int* in_sizes, int n_in,
                              void* d_out, int out_size, void* d_ws, size_t ws_size,
                              hipStream_t stream)
{
    const float* x     = (const float*)d_in[0];
    const float* rbf   = (const float*)d_in[1];
    const int*   idx_j = (const int*)d_in[3];   // idx_i (d_in[2]) unused by ref
    const float* k2f_w = (const float*)d_in[4];
    const float* wi    = (const float*)d_in[5];
    const float* bi    = (const float*)d_in[6];
    const float* wj    = (const float*)d_in[7];
    const float* bj    = (const float*)d_in[8];
    const float* rw1   = (const float*)d_in[9];
    const float* rb1   = (const float*)d_in[10];
    const float* rw2   = (const float*)d_in[11];
    const float* rb2   = (const float*)d_in[12];
    const float* wd    = (const float*)d_in[13];
    const float* bd    = (const float*)d_in[14];
    const float* u     = (const float*)d_in[15];
    float* out = (float*)d_out;

    const size_t NF = (size_t)N_NODES * F;
    float* B0   = (float*)d_ws;          // xi, then m (attn writes in place)
    u16*   XVB  = (u16*)(B0 + NF);       // xv bf16
    u16*   WB   = XVB + NF;              // 7 x [128][128] bf16 weights
    u16*   K2FB = WB + 7 * 16384;        // [128][64] bf16

    hipLaunchKernelGGL(prep_kernel, dim3(120), dim3(256), 0, stream,
                       wi, wj, rw1, rw2, wd, k2f_w, WB, K2FB);

    hipLaunchKernelGGL(in_kernel, dim3(N_NODES / 64), dim3(256), 0, stream,
                       x, WB, bi, bj, B0, XVB);

    hipLaunchKernelGGL(attn_kernel, dim3(N_NODES / 2), dim3(256), 0, stream,
                       B0, XVB, rbf, idx_j, K2FB, B0);

    hipLaunchKernelGGL(tail_kernel, dim3(N_NODES / 64), dim3(256), 0, stream,
                       B0, x, u, WB, rb1, rb2, bd, out);
}